// Round 4
// baseline (116.334 us; speedup 1.0000x reference)
//
#include <hip/hip_runtime.h>
#include <hip/hip_bf16.h>

#define BATCH 8192
#define NF 512
#define NL 1024
#define ATOMS 513

typedef float float4v __attribute__((ext_vector_type(4)));
typedef short short8 __attribute__((ext_vector_type(8)));

// fp32 -> bf16 bits, round-to-nearest-even
__device__ __forceinline__ unsigned short f2bf(float f) {
    union { float f; unsigned int u; } cv; cv.f = f;
    unsigned int u = cv.u;
    u += 0x7fffu + ((u >> 16) & 1u);
    return (unsigned short)(u >> 16);
}

// async 16B/lane global->LDS: lane i lands at ldsbase + i*16 (wave-uniform base)
__device__ __forceinline__ void load_lds16(const unsigned short* g, unsigned short* ldsbase) {
    __builtin_amdgcn_global_load_lds(
        (const __attribute__((address_space(1))) unsigned int*)g,
        (__attribute__((address_space(3))) unsigned int*)ldsbase,
        16, 0, 0);
}

#define N_CONVERT_BLOCKS 2048   // (8192*512)/(256*8)
#define N_SOFTMAX_BLOCKS 1024
#define N_ZERO_BLOCKS    33     // ceil((8192+64)/256)

// ---------------- Kernel 1: fused prep (convert + softmax + zero-init) ----------------
__global__ void prep_kernel(const float* __restrict__ X,
                            const float* __restrict__ logits,
                            unsigned short* __restrict__ Xb,
                            unsigned short* __restrict__ Wb,
                            float* __restrict__ bias,
                            float* __restrict__ sumexp,
                            int* __restrict__ cnt) {
    int bi = blockIdx.x;
    int t  = threadIdx.x;

    if (bi < N_CONVERT_BLOCKS) {
        // role A: X fp32 -> bf16
        size_t i = ((size_t)bi * 256 + t) * 8;
        float4v x0 = *reinterpret_cast<const float4v*>(X + i);
        float4v x1 = *reinterpret_cast<const float4v*>(X + i + 4);
        short8 a;
        a[0] = (short)f2bf(x0[0]); a[1] = (short)f2bf(x0[1]);
        a[2] = (short)f2bf(x0[2]); a[3] = (short)f2bf(x0[3]);
        a[4] = (short)f2bf(x1[0]); a[5] = (short)f2bf(x1[1]);
        a[6] = (short)f2bf(x1[2]); a[7] = (short)f2bf(x1[3]);
        *reinterpret_cast<short8*>(Xb + i) = a;
        return;
    }
    if (bi < N_CONVERT_BLOCKS + N_SOFTMAX_BLOCKS) {
        // role B: per-leaf softmax over 513 atoms
        int l = bi - N_CONVERT_BLOCKS;
        int wave = t >> 6, lane = t & 63;
        const float* row = logits + (size_t)l * ATOMS;
        float v0 = row[t];
        float v1 = row[t + 256];
        float v2 = (t == 0) ? row[512] : -1e30f;

        __shared__ float red[8];
        float m = fmaxf(fmaxf(v0, v1), v2);
#pragma unroll
        for (int o = 32; o > 0; o >>= 1) m = fmaxf(m, __shfl_xor(m, o, 64));
        if (lane == 0) red[wave] = m;
        __syncthreads();
        float mx = fmaxf(fmaxf(red[0], red[1]), fmaxf(red[2], red[3]));

        float e0 = __expf(v0 - mx);
        float e1 = __expf(v1 - mx);
        float e2 = (t == 0) ? __expf(v2 - mx) : 0.f;
        float s = e0 + e1 + e2;
#pragma unroll
        for (int o = 32; o > 0; o >>= 1) s += __shfl_xor(s, o, 64);
        if (lane == 0) red[4 + wave] = s;
        __syncthreads();
        float inv = 1.f / (red[4] + red[5] + red[6] + red[7]);

        unsigned short* wrow = Wb + (size_t)l * NF;
        if (t == 0) {
            bias[l] = e0 * inv;            // atom 0 (constant 1)
            wrow[511] = f2bf(e2 * inv);    // atom 512 -> k=511
        } else {
            wrow[t - 1] = f2bf(e0 * inv);  // atoms 1..255 -> k=0..254
        }
        wrow[t + 255] = f2bf(e1 * inv);    // atoms 256..511 -> k=255..510
        return;
    }
    // role C: zero sum-exp accumulators + arrival counters (ws is poisoned 0xAA)
    int i = (bi - N_CONVERT_BLOCKS - N_SOFTMAX_BLOCKS) * 256 + t;
    if (i < BATCH) sumexp[i] = 0.f;
    else { int j = i - BATCH; if (j < 64) cnt[j] = 0; }
}

// ---------------- Kernel 2: 128x128 MFMA GEMM + fused logsumexp finalize ----------------
// Grid: 512 blocks, mb-fastest (mb = blk&63, nb = blk>>6) for per-XCD L2 locality.
// 4 waves in 2x2; wave computes 64x64 via 4x4 mfma_f32_16x16x32_bf16 tiles.
// LDS As/Bs: 128 rows x 32 bf16 (64B rows), staged via global_load_lds width=16.
// Epilogue: per-row sum of exp(c+bias) -> device atomicAdd; 8th-arriving block
// per row-group takes log and writes out.
__global__ __launch_bounds__(256, 2)
void gemm_lse_kernel(const unsigned short* __restrict__ Xb,
                     const unsigned short* __restrict__ Wb,
                     const float* __restrict__ bias,
                     float* __restrict__ sumexp,
                     int* __restrict__ cnt,
                     float* __restrict__ out) {
    __shared__ unsigned short As[128 * 32];
    __shared__ unsigned short Bs[128 * 32];
    __shared__ float sums[2][128];
    __shared__ int lastFlag;

    int tid  = threadIdx.x;
    int wave = tid >> 6;
    int lane = tid & 63;
    int quad = lane >> 4;
    int l16  = lane & 15;
    int wr = wave >> 1;      // wave row (0..1) -> 64 batch rows
    int wc = wave & 1;       // wave col (0..1) -> 64 leaves

    int mb = blockIdx.x & 63;     // mb-fastest: consecutive blocks share the B panel
    int nb = blockIdx.x >> 6;
    int R0 = mb * 128;
    int N0 = nb * 128;

    // staging addresses: this wave stages rows [wave*32, wave*32+32) of each tile
    int srow  = wave * 32 + (lane >> 2);
    int selem = (lane & 3) * 8;
    const unsigned short* ga = Xb + (size_t)(R0 + srow) * NF + selem;
    const unsigned short* gb = Wb + (size_t)(N0 + srow) * NF + selem;
    unsigned short* la0 = &As[(wave * 32) * 32];
    unsigned short* la1 = &As[(wave * 32 + 16) * 32];
    unsigned short* lb0 = &Bs[(wave * 32) * 32];
    unsigned short* lb1 = &Bs[(wave * 32 + 16) * 32];

    // LDS fragment read pointers (k-offset within 32-slice is constant)
    const unsigned short* pa = &As[(wr * 64 + l16) * 32 + quad * 8];
    const unsigned short* pb = &Bs[(wc * 64 + l16) * 32 + quad * 8];

    // prefetch bias for this wave's 64 leaves
    float bl[4];
#pragma unroll
    for (int nt = 0; nt < 4; ++nt)
        bl[nt] = bias[N0 + wc * 64 + nt * 16 + l16];

    float4v acc[4][4];
#pragma unroll
    for (int mt = 0; mt < 4; ++mt)
#pragma unroll
        for (int nt = 0; nt < 4; ++nt)
            acc[mt][nt] = (float4v){0.f, 0.f, 0.f, 0.f};

    for (int kt = 0; kt < 16; ++kt) {
        load_lds16(ga,           la0);
        load_lds16(ga + 16 * NF, la1);
        load_lds16(gb,           lb0);
        load_lds16(gb + 16 * NF, lb1);
        ga += 32; gb += 32;
        __syncthreads();   // drains vmcnt -> LDS tiles ready

        short8 af[4], bfr[4];
#pragma unroll
        for (int mt = 0; mt < 4; ++mt)
            af[mt] = *reinterpret_cast<const short8*>(pa + mt * 16 * 32);
#pragma unroll
        for (int nt = 0; nt < 4; ++nt)
            bfr[nt] = *reinterpret_cast<const short8*>(pb + nt * 16 * 32);

#pragma unroll
        for (int mt = 0; mt < 4; ++mt)
#pragma unroll
            for (int nt = 0; nt < 4; ++nt)
                acc[mt][nt] = __builtin_amdgcn_mfma_f32_16x16x32_bf16(
                    af[mt], bfr[nt], acc[mt][nt], 0, 0, 0);
        __syncthreads();   // protect LDS before next-kt restage
    }

    // Epilogue: per C-row partial sum of exp(c + bias) over this wave's 64 leaves
    float ps[4][4];
#pragma unroll
    for (int mt = 0; mt < 4; ++mt)
#pragma unroll
        for (int r = 0; r < 4; ++r) ps[mt][r] = 0.f;

#pragma unroll
    for (int nt = 0; nt < 4; ++nt)
#pragma unroll
        for (int mt = 0; mt < 4; ++mt)
#pragma unroll
            for (int r = 0; r < 4; ++r)
                ps[mt][r] += __expf(acc[mt][nt][r] + bl[nt]);

    // reduce across the 16 columns (xor masks < 16 stay within quad group)
#pragma unroll
    for (int m = 1; m < 16; m <<= 1)
#pragma unroll
        for (int mt = 0; mt < 4; ++mt)
#pragma unroll
            for (int r = 0; r < 4; ++r)
                ps[mt][r] += __shfl_xor(ps[mt][r], m, 64);

    if (l16 == 0) {
#pragma unroll
        for (int mt = 0; mt < 4; ++mt)
#pragma unroll
            for (int r = 0; r < 4; ++r)
                sums[wc][wr * 64 + mt * 16 + quad * 4 + r] = ps[mt][r];
    }
    __syncthreads();

    if (tid < 128)
        atomicAdd(&sumexp[R0 + tid], sums[0][tid] + sums[1][tid]);

    // publish, then count arrivals; 8th block finalizes this row-group
    __threadfence();
    __syncthreads();
    if (tid == 0) {
        int old = __hip_atomic_fetch_add(&cnt[mb], 1, __ATOMIC_ACQ_REL,
                                         __HIP_MEMORY_SCOPE_AGENT);
        lastFlag = (old == 7);
    }
    __syncthreads();
    if (lastFlag && tid < 128) {
        float s = __hip_atomic_load(&sumexp[R0 + tid], __ATOMIC_RELAXED,
                                    __HIP_MEMORY_SCOPE_AGENT);
        out[R0 + tid] = logf(s);
    }
}

extern "C" void kernel_launch(void* const* d_in, const int* in_sizes, int n_in,
                              void* d_out, int out_size, void* d_ws, size_t ws_size,
                              hipStream_t stream) {
    const float* X      = (const float*)d_in[0];   // (8192, 512) fp32
    const float* logits = (const float*)d_in[1];   // (1024, 513) fp32
    float* out = (float*)d_out;                    // (8192,) fp32

    char* ws = (char*)d_ws;
    unsigned short* Xb   = (unsigned short*)ws;                                   // 8 MB
    unsigned short* Wb   = (unsigned short*)(ws + (size_t)BATCH * NF * 2);        // 1 MB
    float* bias   = (float*)(ws + (size_t)BATCH * NF * 2 + (size_t)NL * NF * 2);  // 4 KB
    float* sumexp = (float*)((char*)bias + NL * sizeof(float));                   // 32 KB
    int*   cnt    = (int*)((char*)sumexp + BATCH * sizeof(float));                // 256 B

    prep_kernel<<<N_CONVERT_BLOCKS + N_SOFTMAX_BLOCKS + N_ZERO_BLOCKS, 256, 0, stream>>>(
        X, logits, Xb, Wb, bias, sumexp, cnt);
    gemm_lse_kernel<<<(BATCH / 128) * (NL / 128), 256, 0, stream>>>(
        Xb, Wb, bias, sumexp, cnt, out);
}

// Round 5
// 84.842 us; speedup vs baseline: 1.3712x; 1.3712x over previous
//
#include <hip/hip_runtime.h>
#include <hip/hip_bf16.h>

#define BATCH 8192
#define NF 512
#define NL 1024
#define ATOMS 513

typedef float float4v __attribute__((ext_vector_type(4)));
typedef short short8 __attribute__((ext_vector_type(8)));

// fp32 -> bf16 bits, round-to-nearest-even
__device__ __forceinline__ unsigned short f2bf(float f) {
    union { float f; unsigned int u; } cv; cv.f = f;
    unsigned int u = cv.u;
    u += 0x7fffu + ((u >> 16) & 1u);
    return (unsigned short)(u >> 16);
}

// async 16B/lane global->LDS: lane i lands at ldsbase + i*16 (wave-uniform base)
__device__ __forceinline__ void load_lds16(const unsigned short* g, unsigned short* ldsbase) {
    __builtin_amdgcn_global_load_lds(
        (const __attribute__((address_space(1))) unsigned int*)g,
        (__attribute__((address_space(3))) unsigned int*)ldsbase,
        16, 0, 0);
}

// ---------------- Kernel 0: X fp32 -> bf16 ----------------
__global__ void convert_kernel(const float* __restrict__ X,
                               unsigned short* __restrict__ Xb) {
    size_t i = ((size_t)blockIdx.x * 256 + threadIdx.x) * 8;
    float4v x0 = *reinterpret_cast<const float4v*>(X + i);
    float4v x1 = *reinterpret_cast<const float4v*>(X + i + 4);
    short8 a;
    a[0] = (short)f2bf(x0[0]); a[1] = (short)f2bf(x0[1]);
    a[2] = (short)f2bf(x0[2]); a[3] = (short)f2bf(x0[3]);
    a[4] = (short)f2bf(x1[0]); a[5] = (short)f2bf(x1[1]);
    a[6] = (short)f2bf(x1[2]); a[7] = (short)f2bf(x1[3]);
    *reinterpret_cast<short8*>(Xb + i) = a;
}

// ---------------- Kernel 1: per-leaf softmax over 513 atoms ----------------
__global__ void softmax_kernel(const float* __restrict__ logits,
                               unsigned short* __restrict__ Wb,
                               float* __restrict__ bias) {
    int l = blockIdx.x;
    int t = threadIdx.x;
    int wave = t >> 6, lane = t & 63;
    const float* row = logits + (size_t)l * ATOMS;
    float v0 = row[t];
    float v1 = row[t + 256];
    float v2 = (t == 0) ? row[512] : -1e30f;

    __shared__ float red[8];
    float m = fmaxf(fmaxf(v0, v1), v2);
#pragma unroll
    for (int o = 32; o > 0; o >>= 1) m = fmaxf(m, __shfl_xor(m, o, 64));
    if (lane == 0) red[wave] = m;
    __syncthreads();
    float mx = fmaxf(fmaxf(red[0], red[1]), fmaxf(red[2], red[3]));

    float e0 = __expf(v0 - mx);
    float e1 = __expf(v1 - mx);
    float e2 = (t == 0) ? __expf(v2 - mx) : 0.f;
    float s = e0 + e1 + e2;
#pragma unroll
    for (int o = 32; o > 0; o >>= 1) s += __shfl_xor(s, o, 64);
    if (lane == 0) red[4 + wave] = s;
    __syncthreads();
    float inv = 1.f / (red[4] + red[5] + red[6] + red[7]);

    unsigned short* wrow = Wb + (size_t)l * NF;
    if (t == 0) {
        bias[l] = e0 * inv;            // atom 0 (constant 1)
        wrow[511] = f2bf(e2 * inv);    // atom 512 -> k=511
    } else {
        wrow[t - 1] = f2bf(e0 * inv);  // atoms 1..255 -> k=0..254
    }
    wrow[t + 255] = f2bf(e1 * inv);    // atoms 256..511 -> k=255..510
}

// ---------------- Kernel 2: 128x128 MFMA GEMM, double-buffered prefetch ----------------
// Grid: 512 blocks = 64 row-tiles x 8 leaf-tiles, nb-fastest (R3-proven).
// 4 waves in 2x2; wave computes 64x64 via 4x4 mfma_f32_16x16x32_bf16 tiles.
// K-loop: stage(kt+1) AFTER the barrier, compute kt, barrier. One barrier/kt;
// the forced vmcnt(0) drain at the barrier waits on loads that already had the
// whole compute phase in flight (residual stall ~= latency - compute).
__global__ __launch_bounds__(256, 2)
void gemm_lse_kernel(const unsigned short* __restrict__ Xb,
                     const unsigned short* __restrict__ Wb,
                     const float* __restrict__ bias,
                     float* __restrict__ partial) {
    __shared__ unsigned short As[2][128 * 32];
    __shared__ unsigned short Bs[2][128 * 32];
    __shared__ float sums[2][128];

    int tid  = threadIdx.x;
    int wave = tid >> 6;
    int lane = tid & 63;
    int quad = lane >> 4;
    int l16  = lane & 15;
    int wr = wave >> 1;      // wave row (0..1) -> 64 batch rows
    int wc = wave & 1;       // wave col (0..1) -> 64 leaves

    int mb = blockIdx.x >> 3;     // nb-fastest (R3-proven XCD/L2 behavior)
    int nb = blockIdx.x & 7;
    int R0 = mb * 128;
    int N0 = nb * 128;

    // staging: this wave stages rows [wave*32, wave*32+32) of each tile
    int srow  = wave * 32 + (lane >> 2);
    int selem = (lane & 3) * 8;
    const unsigned short* ga = Xb + (size_t)(R0 + srow) * NF + selem;
    const unsigned short* gb = Wb + (size_t)(N0 + srow) * NF + selem;

    float4v acc[4][4];
#pragma unroll
    for (int mt = 0; mt < 4; ++mt)
#pragma unroll
        for (int nt = 0; nt < 4; ++nt)
            acc[mt][nt] = (float4v){0.f, 0.f, 0.f, 0.f};

    // prologue: stage kt=0 into buffer 0
    {
        load_lds16(ga,           &As[0][(wave * 32) * 32]);
        load_lds16(ga + 16 * NF, &As[0][(wave * 32 + 16) * 32]);
        load_lds16(gb,           &Bs[0][(wave * 32) * 32]);
        load_lds16(gb + 16 * NF, &Bs[0][(wave * 32 + 16) * 32]);
    }
    __syncthreads();

    int frag_off = (wr * 64 + l16) * 32 + quad * 8;

    for (int kt = 0; kt < 16; ++kt) {
        int cur = kt & 1;
        // prefetch kt+1 into the other buffer (its previous readers finished
        // before the barrier that ended iteration kt-1)
        if (kt < 15) {
            const unsigned short* a = ga + (kt + 1) * 32;
            const unsigned short* b = gb + (kt + 1) * 32;
            int nxt = cur ^ 1;
            load_lds16(a,           &As[nxt][(wave * 32) * 32]);
            load_lds16(a + 16 * NF, &As[nxt][(wave * 32 + 16) * 32]);
            load_lds16(b,           &Bs[nxt][(wave * 32) * 32]);
            load_lds16(b + 16 * NF, &Bs[nxt][(wave * 32 + 16) * 32]);
        }

        short8 af[4], bfr[4];
#pragma unroll
        for (int mt = 0; mt < 4; ++mt)
            af[mt] = *reinterpret_cast<const short8*>(
                &As[cur][frag_off + (mt * 16 - wr * 64 + wr * 64) * 32 + (mt * 0)]);
#pragma unroll
        for (int mt = 0; mt < 4; ++mt)
            af[mt] = *reinterpret_cast<const short8*>(
                &As[cur][(wr * 64 + mt * 16 + l16) * 32 + quad * 8]);
#pragma unroll
        for (int nt = 0; nt < 4; ++nt)
            bfr[nt] = *reinterpret_cast<const short8*>(
                &Bs[cur][(wc * 64 + nt * 16 + l16) * 32 + quad * 8]);

#pragma unroll
        for (int mt = 0; mt < 4; ++mt)
#pragma unroll
            for (int nt = 0; nt < 4; ++nt)
                acc[mt][nt] = __builtin_amdgcn_mfma_f32_16x16x32_bf16(
                    af[mt], bfr[nt], acc[mt][nt], 0, 0, 0);

        __syncthreads();   // all waves done reading buf cur; prefetch drained
    }

    // Epilogue: per C-row partial sum of exp(c + bias) over this wave's 64 leaves
    float bl[4];
#pragma unroll
    for (int nt = 0; nt < 4; ++nt)
        bl[nt] = bias[N0 + wc * 64 + nt * 16 + l16];

    float ps[4][4];
#pragma unroll
    for (int mt = 0; mt < 4; ++mt)
#pragma unroll
        for (int r = 0; r < 4; ++r) ps[mt][r] = 0.f;

#pragma unroll
    for (int nt = 0; nt < 4; ++nt)
#pragma unroll
        for (int mt = 0; mt < 4; ++mt)
#pragma unroll
            for (int r = 0; r < 4; ++r)
                ps[mt][r] += __expf(acc[mt][nt][r] + bl[nt]);

    // reduce across the 16 columns (xor masks < 16 stay within quad group)
#pragma unroll
    for (int m = 1; m < 16; m <<= 1)
#pragma unroll
        for (int mt = 0; mt < 4; ++mt)
#pragma unroll
            for (int r = 0; r < 4; ++r)
                ps[mt][r] += __shfl_xor(ps[mt][r], m, 64);

    if (l16 == 0) {
#pragma unroll
        for (int mt = 0; mt < 4; ++mt)
#pragma unroll
            for (int r = 0; r < 4; ++r)
                sums[wc][wr * 64 + mt * 16 + quad * 4 + r] = ps[mt][r];
    }
    __syncthreads();
    if (tid < 128)
        partial[(size_t)nb * BATCH + R0 + tid] = sums[0][tid] + sums[1][tid];
}

// ---------------- Kernel 3: combine 8 leaf-panel partials, take log ----------------
__global__ void combine_kernel(const float* __restrict__ partial,
                               float* __restrict__ out) {
    int i = blockIdx.x * 256 + threadIdx.x;
    float s = 0.f;
#pragma unroll
    for (int c = 0; c < 8; ++c) s += partial[(size_t)c * BATCH + i];
    out[i] = logf(s);
}

extern "C" void kernel_launch(void* const* d_in, const int* in_sizes, int n_in,
                              void* d_out, int out_size, void* d_ws, size_t ws_size,
                              hipStream_t stream) {
    const float* X      = (const float*)d_in[0];   // (8192, 512) fp32
    const float* logits = (const float*)d_in[1];   // (1024, 513) fp32
    float* out = (float*)d_out;                    // (8192,) fp32

    char* ws = (char*)d_ws;
    unsigned short* Xb   = (unsigned short*)ws;                                   // 8 MB
    unsigned short* Wb   = (unsigned short*)(ws + (size_t)BATCH * NF * 2);        // 1 MB
    float* bias = (float*)(ws + (size_t)BATCH * NF * 2 + (size_t)NL * NF * 2);    // 4 KB
    float* part = (float*)((char*)bias + NL * sizeof(float));                     // 256 KB

    convert_kernel<<<(BATCH * NF) / (256 * 8), 256, 0, stream>>>(X, Xb);
    softmax_kernel<<<NL, 256, 0, stream>>>(logits, Wb, bias);
    gemm_lse_kernel<<<(BATCH / 128) * (NL / 128), 256, 0, stream>>>(Xb, Wb, bias, part);
    combine_kernel<<<BATCH / 256, 256, 0, stream>>>(part, out);
}